// Round 8
// baseline (1655.265 us; speedup 1.0000x reference)
//
#include <hip/hip_runtime.h>
#include <math.h>

#define BB 8
#define NN 2048
#define DD 512
#define KK 16
#define MM 32
#define BN (BB*NN)

#define QT 64
#define JT 64
#define BK 16

#define KSPLIT 384     // OpenBLAS SGEMM_DEFAULT_Q for ZEN/Haswell targets

#define OUT1 (BN*3)        // q_refine (copy 1)
#define OUT2 (2*BN*3)      // q_refine (copy 2)
#define OUT3 (3*BN*3)      // similar_idx (as float)

// ---------------- Kernel 1: numpy-bit-exact f32 row norms (scalar-8 base) -----
// np.linalg.norm(x,-1) = sqrt(add.reduce(x*x)); numpy pairwise_sum:
// 512 -> (0:256)+(256:512) -> four 128-blocks (B0+B1)+(B2+B3); base n=128 is
// the ordering-stable scalar 8-accumulator block:
//   r[j] = sq[j]; for i=1..15: r[j] += sq[8i+j]
//   block = ((r0+r1)+(r2+r3)) + ((r4+r5)+(r6+r7))
// then correctly-rounded f32 sqrt. 8 lanes per row; lane j owns r_j.
__global__ __launch_bounds__(256) void k_norm_np(const float* __restrict__ ffq,
                                                 const float* __restrict__ ffp,
                                                 float* __restrict__ normq,
                                                 float* __restrict__ normp,
                                                 float* __restrict__ rnp32) {
    const int row = blockIdx.x * 32 + (threadIdx.x >> 3);   // 0..32767
    const int j   = threadIdx.x & 7;
    const bool isQ = row < BN;
    const int r = isQ ? row : row - BN;
    const float* x = (isQ ? ffq : ffp) + (size_t)r * DD;

    float B[4];
#pragma unroll
    for (int t = 0; t < 4; ++t) {
        const float* xb = x + t * 128;
        float e = xb[j];
        float rj = __fmul_rn(e, e);            // r[j] = sq[j]
#pragma unroll
        for (int i = 1; i < 16; ++i) {         // r[j] += sq[8i+j], in order
            float v = xb[8 * i + j];
            rj = __fadd_rn(rj, __fmul_rn(v, v));
        }
        // ((r0+r1)+(r2+r3)) + ((r4+r5)+(r6+r7)) via xor tree in 8 lanes
        float s = __fadd_rn(rj, __shfl_xor(rj, 1, 8));
        float u = __fadd_rn(s,  __shfl_xor(s,  2, 8));
        float w = __fadd_rn(u,  __shfl_xor(u,  4, 8));
        B[t] = w;                               // lane 0 holds the block sum
    }
    if (j == 0) {
        float norm2 = __fadd_rn(__fadd_rn(B[0], B[1]), __fadd_rn(B[2], B[3]));
        float nrm = __fsqrt_rn(norm2);
        if (isQ) { normq[r] = nrm; }
        else {
            normp[r] = nrm;
            rnp32[r] = 1.0f / __fadd_rn(nrm, 1e-8f);   // approx ok (phase-1 only)
        }
    }
}

// ---------------- Kernel 2: fp32 GEMM + fused top-32 candidates ----------------
// Approximate values — only picks a 32-candidate superset of the true top-16
// (rank16->rank32 gap ~0.015 >> 1e-7 f32 noise: safe).
__global__ __launch_bounds__(256) void k_phase1(const float* __restrict__ ffq,
                                                const float* __restrict__ ffp,
                                                const float* __restrict__ rnp32,
                                                int* __restrict__ cand) {
    __shared__ __align__(16) float As[BK][QT];
    __shared__ __align__(16) float Bs[BK][JT];
    __shared__ float simb[QT][JT + 1];
    __shared__ float cval[QT][65];
    __shared__ int   cidx[QT][65];

    const int b  = blockIdx.x & 7;
    const int i0 = (blockIdx.x >> 3) * QT;
    const int tid = threadIdx.x;
    const int tx = tid & 15, ty = tid >> 4;

    const float* Abase = ffq + ((size_t)b * NN + i0) * DD;
    const float* Bbase = ffp + (size_t)b * NN * DD;

    float tv[16]; int tix[16];
#pragma unroll
    for (int r = 0; r < 16; ++r) { tv[r] = -INFINITY; tix[r] = 0; }

    const int lrow = tid >> 2;
    const int lseg = (tid & 3) * 4;
    const int qq = tid >> 2;
    const int st = tid & 3;

    for (int jt = 0; jt < NN / JT; ++jt) {
        const int j0 = jt * JT;
        float acc[4][4];
#pragma unroll
        for (int r = 0; r < 4; ++r)
#pragma unroll
            for (int c = 0; c < 4; ++c) acc[r][c] = 0.0f;

        for (int kt = 0; kt < DD / BK; ++kt) {
            const int k0 = kt * BK;
            __syncthreads();
            float4 av = *(const float4*)(Abase + (size_t)lrow * DD + k0 + lseg);
            float4 bv = *(const float4*)(Bbase + (size_t)(j0 + lrow) * DD + k0 + lseg);
            As[lseg + 0][lrow] = av.x; As[lseg + 1][lrow] = av.y;
            As[lseg + 2][lrow] = av.z; As[lseg + 3][lrow] = av.w;
            Bs[lseg + 0][lrow] = bv.x; Bs[lseg + 1][lrow] = bv.y;
            Bs[lseg + 2][lrow] = bv.z; Bs[lseg + 3][lrow] = bv.w;
            __syncthreads();
#pragma unroll
            for (int kk = 0; kk < BK; ++kk) {
                const float4 a4 = *(const float4*)&As[kk][ty * 4];
                const float4 b4 = *(const float4*)&Bs[kk][tx * 4];
                const float ar[4] = {a4.x, a4.y, a4.z, a4.w};
                const float br[4] = {b4.x, b4.y, b4.z, b4.w};
#pragma unroll
                for (int r = 0; r < 4; ++r)
#pragma unroll
                    for (int c = 0; c < 4; ++c)
                        acc[r][c] = fmaf(ar[r], br[c], acc[r][c]);
            }
        }
        float rp[4];
#pragma unroll
        for (int c = 0; c < 4; ++c) rp[c] = rnp32[b * NN + j0 + tx * 4 + c];
#pragma unroll
        for (int r = 0; r < 4; ++r)
#pragma unroll
            for (int c = 0; c < 4; ++c)
                simb[ty * 4 + r][tx * 4 + c] = acc[r][c] * rp[c];
        __syncthreads();

#pragma unroll
        for (int t = 0; t < 16; ++t) {
            const int jl = st * 16 + t;
            const float v = simb[qq][jl];
            const int jg = j0 + jl;
            if (v > tv[0]) {
#pragma unroll
                for (int r = 0; r < 15; ++r) {
                    const bool up = tv[r + 1] < v;
                    const float nv = up ? tv[r + 1] : ((tv[r] < v) ? v : tv[r]);
                    const int   ni = up ? tix[r + 1] : ((tv[r] < v) ? jg : tix[r]);
                    tv[r] = nv; tix[r] = ni;
                }
                if (tv[15] < v) { tv[15] = v; tix[15] = jg; }
            }
        }
        __syncthreads();
    }

#pragma unroll
    for (int t = 0; t < 16; ++t) {
        cval[qq][st * 16 + t] = tv[t];
        cidx[qq][st * 16 + t] = tix[t];
    }
    __syncthreads();
    if (tid < QT) {
        const size_t gi = ((size_t)b * NN + i0 + tid) * MM;
        for (int m = 0; m < MM; ++m) {
            float best = -INFINITY; int bx = 0;
            for (int x = 0; x < 64; ++x) {
                float v = cval[tid][x];
                if (v > best) { best = v; bx = x; }
            }
            cand[gi + m] = cidx[tid][bx];
            cval[tid][bx] = -INFINITY;
        }
    }
}

// ---------------- 3x3 inverse (adjugate) apply ----------------
__device__ inline void inv3_apply(const double* a, double x0, double x1, double x2,
                                  double& y0, double& y1, double& y2) {
    double c00 = a[4]*a[8] - a[5]*a[7];
    double c01 = a[2]*a[7] - a[1]*a[8];
    double c02 = a[1]*a[5] - a[2]*a[4];
    double c10 = a[5]*a[6] - a[3]*a[8];
    double c11 = a[0]*a[8] - a[2]*a[6];
    double c12 = a[2]*a[3] - a[0]*a[5];
    double c20 = a[3]*a[7] - a[4]*a[6];
    double c21 = a[1]*a[6] - a[0]*a[7];
    double c22 = a[0]*a[4] - a[1]*a[3];
    double det = a[0]*c00 + a[1]*c10 + a[2]*c20;
    double id = 1.0 / det;
    y0 = (c00*x0 + c01*x1 + c02*x2) * id;
    y1 = (c10*x0 + c11*x1 + c12*x2) * id;
    y2 = (c20*x0 + c21*x1 + c22*x2) * id;
}

// ---------------- Kernel 3: OpenBLAS-sgemm f32 rescore + top-16 + epilogue ----
// np-ref w1 = batched cblas_sgemm. Per C element, OpenBLAS blocks K into
// panels of SGEMM_DEFAULT_Q=384 (ZEN target): panel 1 writes
// C = fl(fma-chain(d=0..383)), panel 2 accumulates C = fl(C + fma-chain(
// d=384..511)) — each chain a single-accumulator ascending-k vfmadd231ps
// sequence, with one *extra rounding* at the d=384 boundary.
// Operands bit-match numpy: x / (norm_scalar8 + 1e-8f), rounded divide.
// TIE-BREAK: value desc, index asc (stable argsort-desc / lax.top_k port).
__global__ __launch_bounds__(256) void k_phase2(
        const float* __restrict__ qin, const float* __restrict__ ffq,
        const float* __restrict__ ffp, const float* __restrict__ R1,
        const float* __restrict__ R2, const int* __restrict__ cent,
        const float* __restrict__ W, const float* __restrict__ bvec,
        const float* __restrict__ normq, const float* __restrict__ normp,
        const int* __restrict__ cand, float* __restrict__ out) {
    const int b = blockIdx.x & 7;
    const int i = blockIdx.x >> 3;
    const int tid = threadIdx.x;
    const size_t qi = (size_t)b * NN + i;

    __shared__ float sfq[DD];      // raw ffq row (for refine epilogue)
    __shared__ float sfqn[DD];     // np-exact normalized row
    __shared__ int cj[MM];
    __shared__ float pden_s[MM];
    __shared__ float sv[MM];
    __shared__ int sel[KK];
    __shared__ float meanf[DD], maxf[DD];
    __shared__ float red[3][4];

    const float qden = __fadd_rn(normq[qi], 1e-8f);
    for (int d = tid; d < DD; d += 256) {
        float xv = ffq[qi * DD + d];
        sfq[d] = xv;
        sfqn[d] = __fdiv_rn(xv, qden);
    }
    if (tid < MM) {
        int j = cand[qi * MM + tid];
        cj[tid] = j;
        pden_s[tid] = __fadd_rn(normp[(size_t)b * NN + j], 1e-8f);
    }
    __syncthreads();

    if (tid < MM) {   // one lane per candidate: two K-panel FMA chains
        const int j = cj[tid];
        const float pd = pden_s[tid];
        const float* fp = ffp + ((size_t)b * NN + j) * DD;
        float acc1 = 0.0f;
        for (int d = 0; d < KSPLIT; ++d) {
            acc1 = fmaf(sfqn[d], __fdiv_rn(fp[d], pd), acc1);
        }
        float acc2 = 0.0f;
        for (int d = KSPLIT; d < DD; ++d) {
            acc2 = fmaf(sfqn[d], __fdiv_rn(fp[d], pd), acc2);
        }
        sv[tid] = __fadd_rn(acc1, acc2);   // panel-boundary rounding
    }
    __syncthreads();

    if (tid < MM) {   // rank: value desc, index asc among bit-equal values
        const float v = sv[tid]; const int jj = cj[tid];
        int rank = 0;
        for (int t = 0; t < MM; ++t) {
            const float vt = sv[t]; const int jo = cj[t];
            rank += (vt > v) || (vt == v && jo < jj);
        }
        if (rank < KK) {
            sel[rank] = jj;
            out[(size_t)OUT3 + qi * KK + rank] = (float)jj;
        }
    }
    __syncthreads();

    // avg+max pool over the 16 selected ffp rows (loose threshold)
    for (int d = tid; d < DD; d += 256) {
        float sum = 0.0f, mx = -INFINITY;
#pragma unroll
        for (int k = 0; k < KK; ++k) {
            float v = ffp[((size_t)b * NN + sel[k]) * DD + d];
            sum += v; mx = fmaxf(mx, v);
        }
        meanf[d] = sum * (1.0f / 16.0f);
        maxf[d]  = mx;
    }
    __syncthreads();

    float a0 = 0.f, a1 = 0.f, a2 = 0.f;
    for (int d = tid; d < DD; d += 256) {
        const float x = sfq[d], m = meanf[d], mx = maxf[d];
        a0 = fmaf(W[d],        x, a0); a0 = fmaf(W[512 + d],        m, a0); a0 = fmaf(W[1024 + d],        mx, a0);
        a1 = fmaf(W[1536 + d], x, a1); a1 = fmaf(W[1536 + 512 + d], m, a1); a1 = fmaf(W[1536 + 1024 + d], mx, a1);
        a2 = fmaf(W[3072 + d], x, a2); a2 = fmaf(W[3072 + 512 + d], m, a2); a2 = fmaf(W[3072 + 1024 + d], mx, a2);
    }
#pragma unroll
    for (int off = 32; off > 0; off >>= 1) {
        a0 += __shfl_down(a0, off, 64);
        a1 += __shfl_down(a1, off, 64);
        a2 += __shfl_down(a2, off, 64);
    }
    const int lane = tid & 63, wid = tid >> 6;
    if (lane == 0) { red[0][wid] = a0; red[1][wid] = a1; red[2][wid] = a2; }
    __syncthreads();

    if (tid == 0) {
        double v0 = (double)bvec[0] + red[0][0] + red[0][1] + red[0][2] + red[0][3];
        double v1 = (double)bvec[1] + red[1][0] + red[1][1] + red[1][2] + red[1][3];
        double v2 = (double)bvec[2] + red[2][0] + red[2][1] + red[2][2] + red[2][3];
        double r1[9], r2[9];
#pragma unroll
        for (int t = 0; t < 9; ++t) { r1[t] = R1[qi * 9 + t]; r2[t] = R2[qi * 9 + t]; }
        double u0, u1, u2, w0, w1, w2;
        inv3_apply(r1, v0, v1, v2, u0, u1, u2);
        inv3_apply(r2, u0, u1, u2, w0, w1, w2);
        const float mask = (cent[qi] >= NN) ? 1.0f : 0.0f;
        const float q0 = qin[qi * 3 + 0], q1 = qin[qi * 3 + 1], q2 = qin[qi * 3 + 2];
        out[qi * 3 + 0] = q0; out[qi * 3 + 1] = q1; out[qi * 3 + 2] = q2;
        const float o0 = q0 + (float)w0 * mask;
        const float o1 = q1 + (float)w1 * mask;
        const float o2 = q2 + (float)w2 * mask;
        out[OUT1 + qi * 3 + 0] = o0; out[OUT1 + qi * 3 + 1] = o1; out[OUT1 + qi * 3 + 2] = o2;
        out[OUT2 + qi * 3 + 0] = o0; out[OUT2 + qi * 3 + 1] = o1; out[OUT2 + qi * 3 + 2] = o2;
    }
}

extern "C" void kernel_launch(void* const* d_in, const int* in_sizes, int n_in,
                              void* d_out, int out_size, void* d_ws, size_t ws_size,
                              hipStream_t stream) {
    (void)in_sizes; (void)n_in; (void)out_size; (void)ws_size;
    const float* q   = (const float*)d_in[1];
    const float* ffp = (const float*)d_in[2];
    const float* ffq = (const float*)d_in[3];
    const float* R1  = (const float*)d_in[4];
    const float* R2  = (const float*)d_in[5];
    const int*   ct  = (const int*)d_in[6];
    const float* W   = (const float*)d_in[7];
    const float* bb  = (const float*)d_in[8];
    float* out = (float*)d_out;

    float* normq = (float*)d_ws;           // BN
    float* normp = normq + BN;             // BN
    float* rnp32 = normp + BN;             // BN
    int*   cand  = (int*)(rnp32 + BN);     // BN*MM

    k_norm_np<<<dim3((2 * BN) / 32), dim3(256), 0, stream>>>(ffq, ffp, normq, normp, rnp32);
    k_phase1 <<<dim3(BB * (NN / QT)), dim3(256), 0, stream>>>(ffq, ffp, rnp32, cand);
    k_phase2 <<<dim3(BB * NN), dim3(256), 0, stream>>>(q, ffq, ffp, R1, R2, ct, W, bb,
                                                       normq, normp, cand, out);
}

// Round 9
// 1309.194 us; speedup vs baseline: 1.2643x; 1.2643x over previous
//
#include <hip/hip_runtime.h>
#include <math.h>

#define BB 8
#define NN 2048
#define DD 512
#define KK 16
#define BN (BB*NN)

#define QT 64
#define JTILE 64
#define BK 16
#define JSPLIT 4
#define JRANGE (NN/JSPLIT)      // 512 candidates per block
#define MM (16*JSPLIT)          // 64 candidates per query into phase-2
#define LDP 68                  // padded LDS row stride (floats): 2-way-free staging
#define SIMP 68                 // simb row stride (floats): 16B-aligned float4 rows

#define KSPLIT 384              // OpenBLAS SGEMM_DEFAULT_Q (ZEN) — DO NOT CHANGE

#define OUT1 (BN*3)             // q_refine (copy 1)
#define OUT2 (2*BN*3)           // q_refine (copy 2)
#define OUT3 (3*BN*3)           // similar_idx (as float)

// ---------------- Kernel 1: numpy-bit-exact f32 row norms (scalar-8 base) -----
// VERIFIED r8: np pairwise_sum 512->256->128, base = scalar 8-accumulator
// block, combine ((r0+r1)+(r2+r3))+((r4+r5)+(r6+r7)), blocks (B0+B1)+(B2+B3),
// then correctly-rounded sqrt. DO NOT CHANGE ARITHMETIC.
__global__ __launch_bounds__(256) void k_norm_np(const float* __restrict__ ffq,
                                                 const float* __restrict__ ffp,
                                                 float* __restrict__ normq,
                                                 float* __restrict__ normp,
                                                 float* __restrict__ rnp32) {
    const int row = blockIdx.x * 32 + (threadIdx.x >> 3);   // 0..32767
    const int j   = threadIdx.x & 7;
    const bool isQ = row < BN;
    const int r = isQ ? row : row - BN;
    const float* x = (isQ ? ffq : ffp) + (size_t)r * DD;

    float B[4];
#pragma unroll
    for (int t = 0; t < 4; ++t) {
        const float* xb = x + t * 128;
        float e = xb[j];
        float rj = __fmul_rn(e, e);
#pragma unroll
        for (int i = 1; i < 16; ++i) {
            float v = xb[8 * i + j];
            rj = __fadd_rn(rj, __fmul_rn(v, v));
        }
        float s = __fadd_rn(rj, __shfl_xor(rj, 1, 8));
        float u = __fadd_rn(s,  __shfl_xor(s,  2, 8));
        float w = __fadd_rn(u,  __shfl_xor(u,  4, 8));
        B[t] = w;
    }
    if (j == 0) {
        float norm2 = __fadd_rn(__fadd_rn(B[0], B[1]), __fadd_rn(B[2], B[3]));
        float nrm = __fsqrt_rn(norm2);
        if (isQ) { normq[r] = nrm; }
        else {
            normp[r] = nrm;
            rnp32[r] = 1.0f / __fadd_rn(nrm, 1e-8f);   // approx ok (phase-1 only)
        }
    }
}

// ---------------- Kernel 2: fp32 GEMM + fused per-split top-16 -----------------
// 4-way j-split: block handles 64 queries x 512 candidates; per-split exact
// top-16 by approx fp32 score; union over 4 splits (64 cands) superset of the
// true top-16 with huge margin. Occupancy: 1024 blocks = 4/CU (was 1/CU).
__global__ __launch_bounds__(256, 4) void k_phase1(const float* __restrict__ ffq,
                                                   const float* __restrict__ ffp,
                                                   const float* __restrict__ rnp32,
                                                   unsigned short* __restrict__ cand) {
    __shared__ __align__(16) float As[BK * LDP];
    __shared__ __align__(16) float Bs[BK * LDP];
    __shared__ __align__(16) float simb[QT * SIMP];

    const int b  = blockIdx.x & 7;                   // batch -> XCD locality
    const int i0 = ((blockIdx.x >> 3) & 31) * QT;
    const int js = blockIdx.x >> 8;                  // 0..3 j-split
    const int tid = threadIdx.x;
    const int tx = tid & 15, ty = tid >> 4;

    const float* Abase = ffq + ((size_t)b * NN + i0) * DD;
    const float* Bbase = ffp + (size_t)b * NN * DD;

    float tv[16]; int tix[16];                       // ascending top-16
#pragma unroll
    for (int r = 0; r < 16; ++r) { tv[r] = -INFINITY; tix[r] = -1; }

    const int lrow = tid >> 2;          // 0..63 staging row
    const int lseg = (tid & 3) * 4;     // k sub-offset
    const int qq = tid >> 2;            // query this thread selects for
    const int st = tid & 3;             // stripe 0..3

    for (int jt = 0; jt < JRANGE / JTILE; ++jt) {    // 8 tiles
        const int j0 = js * JRANGE + jt * JTILE;
        float acc[4][4];
#pragma unroll
        for (int r = 0; r < 4; ++r)
#pragma unroll
            for (int c = 0; c < 4; ++c) acc[r][c] = 0.0f;

        for (int kt = 0; kt < DD / BK; ++kt) {
            const int k0 = kt * BK;
            __syncthreads();
            float4 av = *(const float4*)(Abase + (size_t)lrow * DD + k0 + lseg);
            float4 bv = *(const float4*)(Bbase + (size_t)(j0 + lrow) * DD + k0 + lseg);
            As[(lseg + 0) * LDP + lrow] = av.x; As[(lseg + 1) * LDP + lrow] = av.y;
            As[(lseg + 2) * LDP + lrow] = av.z; As[(lseg + 3) * LDP + lrow] = av.w;
            Bs[(lseg + 0) * LDP + lrow] = bv.x; Bs[(lseg + 1) * LDP + lrow] = bv.y;
            Bs[(lseg + 2) * LDP + lrow] = bv.z; Bs[(lseg + 3) * LDP + lrow] = bv.w;
            __syncthreads();
#pragma unroll
            for (int kk = 0; kk < BK; ++kk) {
                const float4 a4 = *(const float4*)&As[kk * LDP + ty * 4];
                const float4 b4 = *(const float4*)&Bs[kk * LDP + tx * 4];
                const float ar[4] = {a4.x, a4.y, a4.z, a4.w};
                const float br[4] = {b4.x, b4.y, b4.z, b4.w};
#pragma unroll
                for (int r = 0; r < 4; ++r)
#pragma unroll
                    for (int c = 0; c < 4; ++c)
                        acc[r][c] = fmaf(ar[r], br[c], acc[r][c]);
            }
        }
        // scale by 1/||fp_j|| and publish as float4 rows (no 8-way conflicts)
        float rp[4];
#pragma unroll
        for (int c = 0; c < 4; ++c) rp[c] = rnp32[b * NN + j0 + tx * 4 + c];
#pragma unroll
        for (int r = 0; r < 4; ++r) {
            float4 v4;
            v4.x = acc[r][0] * rp[0]; v4.y = acc[r][1] * rp[1];
            v4.z = acc[r][2] * rp[2]; v4.w = acc[r][3] * rp[3];
            *(float4*)&simb[(ty * 4 + r) * SIMP + tx * 4] = v4;
        }
        __syncthreads();

        // per-thread top-16 over this thread's 16-col stripe of its query
#pragma unroll
        for (int t = 0; t < 16; ++t) {
            const int jl = st * 16 + t;
            const float v = simb[qq * SIMP + jl];
            const int jg = j0 + jl;
            if (v > tv[0]) {
#pragma unroll
                for (int r = 0; r < 15; ++r) {
                    const bool up = tv[r + 1] < v;
                    const float nv = up ? tv[r + 1] : ((tv[r] < v) ? v : tv[r]);
                    const int   ni = up ? tix[r + 1] : ((tv[r] < v) ? jg : tix[r]);
                    tv[r] = nv; tix[r] = ni;
                }
                if (tv[15] < v) { tv[15] = v; tix[15] = jg; }
            }
        }
        __syncthreads();   // selection reads done before simb rewrite next tile
    }

    // merge 4 sorted 16-lists (lanes st=0..3 of query qq) -> split top-16
    int p = 15;
    const size_t base = ((size_t)b * NN + i0 + qq) * MM + (size_t)js * 16;
    for (int m = 0; m < 16; ++m) {
        float cv = (p >= 0) ? tv[p] : -INFINITY;
        int   ci = (p >= 0) ? tix[p] : -1;
        float ov; int oi;
        ov = __shfl_xor(cv, 1, 4); oi = __shfl_xor(ci, 1, 4);
        if (ov > cv || (ov == cv && (unsigned)oi < (unsigned)ci)) { cv = ov; ci = oi; }
        ov = __shfl_xor(cv, 2, 4); oi = __shfl_xor(ci, 2, 4);
        if (ov > cv || (ov == cv && (unsigned)oi < (unsigned)ci)) { cv = ov; ci = oi; }
        if (p >= 0 && tv[p] == cv && tix[p] == ci) --p;   // unique (idx distinct)
        if (st == 0) cand[base + m] = (unsigned short)ci;
    }
}

// ---------------- 3x3 inverse (adjugate) apply ----------------
__device__ inline void inv3_apply(const double* a, double x0, double x1, double x2,
                                  double& y0, double& y1, double& y2) {
    double c00 = a[4]*a[8] - a[5]*a[7];
    double c01 = a[2]*a[7] - a[1]*a[8];
    double c02 = a[1]*a[5] - a[2]*a[4];
    double c10 = a[5]*a[6] - a[3]*a[8];
    double c11 = a[0]*a[8] - a[2]*a[6];
    double c12 = a[2]*a[3] - a[0]*a[5];
    double c20 = a[3]*a[7] - a[4]*a[6];
    double c21 = a[1]*a[6] - a[0]*a[7];
    double c22 = a[0]*a[4] - a[1]*a[3];
    double det = a[0]*c00 + a[1]*c10 + a[2]*c20;
    double id = 1.0 / det;
    y0 = (c00*x0 + c01*x1 + c02*x2) * id;
    y1 = (c10*x0 + c11*x1 + c12*x2) * id;
    y2 = (c20*x0 + c21*x1 + c22*x2) * id;
}

// ---------------- Kernel 3: OpenBLAS-sgemm f32 rescore + top-16 + epilogue ----
// VERIFIED r8 arithmetic: per candidate, two ascending-k FMA chains split at
// d=384 (SGEMM_DEFAULT_Q panels), one rounded add at the boundary. Operands
// x/(norm_scalar8 + 1e-8f) with rounded divide. Tie: value desc, index asc.
// DO NOT CHANGE ARITHMETIC. (Now 64 candidates from the 4-way j-split.)
__global__ __launch_bounds__(256) void k_phase2(
        const float* __restrict__ qin, const float* __restrict__ ffq,
        const float* __restrict__ ffp, const float* __restrict__ R1,
        const float* __restrict__ R2, const int* __restrict__ cent,
        const float* __restrict__ W, const float* __restrict__ bvec,
        const float* __restrict__ normq, const float* __restrict__ normp,
        const unsigned short* __restrict__ cand, float* __restrict__ out) {
    const int b = blockIdx.x & 7;
    const int i = blockIdx.x >> 3;
    const int tid = threadIdx.x;
    const size_t qi = (size_t)b * NN + i;

    __shared__ float sfq[DD];
    __shared__ float sfqn[DD];
    __shared__ int cj[MM];
    __shared__ float pden_s[MM];
    __shared__ float sv[MM];
    __shared__ int sel[KK];
    __shared__ float meanf[DD], maxf[DD];
    __shared__ float red[3][4];

    const float qden = __fadd_rn(normq[qi], 1e-8f);
    for (int d = tid; d < DD; d += 256) {
        float xv = ffq[qi * DD + d];
        sfq[d] = xv;
        sfqn[d] = __fdiv_rn(xv, qden);
    }
    if (tid < MM) {
        int j = (int)cand[qi * MM + tid];
        cj[tid] = j;
        pden_s[tid] = __fadd_rn(normp[(size_t)b * NN + j], 1e-8f);
    }
    __syncthreads();

    if (tid < MM) {   // one lane per candidate: two K-panel FMA chains
        const int j = cj[tid];
        const float pd = pden_s[tid];
        const float* fp = ffp + ((size_t)b * NN + j) * DD;
        float acc1 = 0.0f;
        for (int d = 0; d < KSPLIT; ++d) {
            acc1 = fmaf(sfqn[d], __fdiv_rn(fp[d], pd), acc1);
        }
        float acc2 = 0.0f;
        for (int d = KSPLIT; d < DD; ++d) {
            acc2 = fmaf(sfqn[d], __fdiv_rn(fp[d], pd), acc2);
        }
        sv[tid] = __fadd_rn(acc1, acc2);   // panel-boundary rounding
    }
    __syncthreads();

    if (tid < MM) {   // rank: value desc, index asc among bit-equal values
        const float v = sv[tid]; const int jj = cj[tid];
        int rank = 0;
        for (int t = 0; t < MM; ++t) {
            const float vt = sv[t]; const int jo = cj[t];
            rank += (vt > v) || (vt == v && jo < jj);
        }
        if (rank < KK) {
            sel[rank] = jj;
            out[(size_t)OUT3 + qi * KK + rank] = (float)jj;
        }
    }
    __syncthreads();

    // avg+max pool over the 16 selected ffp rows (loose threshold)
    for (int d = tid; d < DD; d += 256) {
        float sum = 0.0f, mx = -INFINITY;
#pragma unroll
        for (int k = 0; k < KK; ++k) {
            float v = ffp[((size_t)b * NN + sel[k]) * DD + d];
            sum += v; mx = fmaxf(mx, v);
        }
        meanf[d] = sum * (1.0f / 16.0f);
        maxf[d]  = mx;
    }
    __syncthreads();

    float a0 = 0.f, a1 = 0.f, a2 = 0.f;
    for (int d = tid; d < DD; d += 256) {
        const float x = sfq[d], m = meanf[d], mx = maxf[d];
        a0 = fmaf(W[d],        x, a0); a0 = fmaf(W[512 + d],        m, a0); a0 = fmaf(W[1024 + d],        mx, a0);
        a1 = fmaf(W[1536 + d], x, a1); a1 = fmaf(W[1536 + 512 + d], m, a1); a1 = fmaf(W[1536 + 1024 + d], mx, a1);
        a2 = fmaf(W[3072 + d], x, a2); a2 = fmaf(W[3072 + 512 + d], m, a2); a2 = fmaf(W[3072 + 1024 + d], mx, a2);
    }
#pragma unroll
    for (int off = 32; off > 0; off >>= 1) {
        a0 += __shfl_down(a0, off, 64);
        a1 += __shfl_down(a1, off, 64);
        a2 += __shfl_down(a2, off, 64);
    }
    const int lane = tid & 63, wid = tid >> 6;
    if (lane == 0) { red[0][wid] = a0; red[1][wid] = a1; red[2][wid] = a2; }
    __syncthreads();

    if (tid == 0) {
        double v0 = (double)bvec[0] + red[0][0] + red[0][1] + red[0][2] + red[0][3];
        double v1 = (double)bvec[1] + red[1][0] + red[1][1] + red[1][2] + red[1][3];
        double v2 = (double)bvec[2] + red[2][0] + red[2][1] + red[2][2] + red[2][3];
        double r1[9], r2[9];
#pragma unroll
        for (int t = 0; t < 9; ++t) { r1[t] = R1[qi * 9 + t]; r2[t] = R2[qi * 9 + t]; }
        double u0, u1, u2, w0, w1, w2;
        inv3_apply(r1, v0, v1, v2, u0, u1, u2);
        inv3_apply(r2, u0, u1, u2, w0, w1, w2);
        const float mask = (cent[qi] >= NN) ? 1.0f : 0.0f;
        const float q0 = qin[qi * 3 + 0], q1 = qin[qi * 3 + 1], q2 = qin[qi * 3 + 2];
        out[qi * 3 + 0] = q0; out[qi * 3 + 1] = q1; out[qi * 3 + 2] = q2;
        const float o0 = q0 + (float)w0 * mask;
        const float o1 = q1 + (float)w1 * mask;
        const float o2 = q2 + (float)w2 * mask;
        out[OUT1 + qi * 3 + 0] = o0; out[OUT1 + qi * 3 + 1] = o1; out[OUT1 + qi * 3 + 2] = o2;
        out[OUT2 + qi * 3 + 0] = o0; out[OUT2 + qi * 3 + 1] = o1; out[OUT2 + qi * 3 + 2] = o2;
    }
}

extern "C" void kernel_launch(void* const* d_in, const int* in_sizes, int n_in,
                              void* d_out, int out_size, void* d_ws, size_t ws_size,
                              hipStream_t stream) {
    (void)in_sizes; (void)n_in; (void)out_size; (void)ws_size;
    const float* q   = (const float*)d_in[1];
    const float* ffp = (const float*)d_in[2];
    const float* ffq = (const float*)d_in[3];
    const float* R1  = (const float*)d_in[4];
    const float* R2  = (const float*)d_in[5];
    const int*   ct  = (const int*)d_in[6];
    const float* W   = (const float*)d_in[7];
    const float* bb  = (const float*)d_in[8];
    float* out = (float*)d_out;

    float* normq = (float*)d_ws;                       // BN f32
    float* normp = normq + BN;                         // BN f32
    float* rnp32 = normp + BN;                         // BN f32
    unsigned short* cand = (unsigned short*)(rnp32 + BN);  // BN*MM u16 (2 MB)

    k_norm_np<<<dim3((2 * BN) / 32), dim3(256), 0, stream>>>(ffq, ffp, normq, normp, rnp32);
    k_phase1 <<<dim3(BB * (NN / QT) * JSPLIT), dim3(256), 0, stream>>>(ffq, ffp, rnp32, cand);
    k_phase2 <<<dim3(BB * NN), dim3(256), 0, stream>>>(q, ffq, ffp, R1, R2, ct, W, bb,
                                                       normq, normp, cand, out);
}

// Round 10
// 736.100 us; speedup vs baseline: 2.2487x; 1.7786x over previous
//
#include <hip/hip_runtime.h>
#include <math.h>

#define BB 8
#define NN 2048
#define DD 512
#define KK 16
#define BN (BB*NN)

#define QT 64
#define JSPLIT 4
#define JRANGE (NN/JSPLIT)      // 512 candidates per block
#define MM (16*JSPLIT)          // 64 candidates per query into phase-2
#define SIMP 68                 // simb row stride (floats)

#define KSPLIT 384              // OpenBLAS SGEMM_DEFAULT_Q (ZEN) — DO NOT CHANGE

#define OUT1 (BN*3)
#define OUT2 (2*BN*3)
#define OUT3 (3*BN*3)

typedef __attribute__((ext_vector_type(8))) short bf16x8;
typedef __attribute__((ext_vector_type(4))) float f32x4;

__device__ inline unsigned short cvt_bf16(float f) {   // RNE, finite inputs
    unsigned int u = __float_as_uint(f);
    return (unsigned short)((u + 0x7fffu + ((u >> 16) & 1u)) >> 16);
}

// ---------------- Kernel 1: numpy-bit-exact f32 row norms (scalar-8 base) -----
// VERIFIED r8. DO NOT CHANGE ARITHMETIC.
__global__ __launch_bounds__(256) void k_norm_np(const float* __restrict__ ffq,
                                                 const float* __restrict__ ffp,
                                                 float* __restrict__ normq,
                                                 float* __restrict__ normp,
                                                 float* __restrict__ rnp32) {
    const int row = blockIdx.x * 32 + (threadIdx.x >> 3);
    const int j   = threadIdx.x & 7;
    const bool isQ = row < BN;
    const int r = isQ ? row : row - BN;
    const float* x = (isQ ? ffq : ffp) + (size_t)r * DD;

    float B[4];
#pragma unroll
    for (int t = 0; t < 4; ++t) {
        const float* xb = x + t * 128;
        float e = xb[j];
        float rj = __fmul_rn(e, e);
#pragma unroll
        for (int i = 1; i < 16; ++i) {
            float v = xb[8 * i + j];
            rj = __fadd_rn(rj, __fmul_rn(v, v));
        }
        float s = __fadd_rn(rj, __shfl_xor(rj, 1, 8));
        float u = __fadd_rn(s,  __shfl_xor(s,  2, 8));
        float w = __fadd_rn(u,  __shfl_xor(u,  4, 8));
        B[t] = w;
    }
    if (j == 0) {
        float norm2 = __fadd_rn(__fadd_rn(B[0], B[1]), __fadd_rn(B[2], B[3]));
        float nrm = __fsqrt_rn(norm2);
        if (isQ) { normq[r] = nrm; }
        else {
            normp[r] = nrm;
            rnp32[r] = 1.0f / __fadd_rn(nrm, 1e-8f);
        }
    }
}

// ---------------- Kernel 1b: normalized f32 (exact bits) + bf16 copies --------
__global__ __launch_bounds__(256) void k_normalize(const float* __restrict__ ffq,
                                                   const float* __restrict__ ffp,
                                                   const float* __restrict__ normq,
                                                   const float* __restrict__ normp,
                                                   float* __restrict__ fqn,
                                                   float* __restrict__ fpn,
                                                   unsigned short* __restrict__ fqb,
                                                   unsigned short* __restrict__ fpb) {
    const size_t e4 = ((size_t)blockIdx.x * 256 + threadIdx.x) * 4;
    if (e4 >= (size_t)BN * DD) return;
    const int row = (int)(e4 >> 9);
    {
        float4 v = *(const float4*)(ffq + e4);
        float den = __fadd_rn(normq[row], 1e-8f);
        float4 o;
        o.x = __fdiv_rn(v.x, den); o.y = __fdiv_rn(v.y, den);
        o.z = __fdiv_rn(v.z, den); o.w = __fdiv_rn(v.w, den);
        *(float4*)(fqn + e4) = o;
        ushort4 b; b.x = cvt_bf16(o.x); b.y = cvt_bf16(o.y);
        b.z = cvt_bf16(o.z); b.w = cvt_bf16(o.w);
        *(ushort4*)(fqb + e4) = b;
    }
    {
        float4 v = *(const float4*)(ffp + e4);
        float den = __fadd_rn(normp[row], 1e-8f);
        float4 o;
        o.x = __fdiv_rn(v.x, den); o.y = __fdiv_rn(v.y, den);
        o.z = __fdiv_rn(v.z, den); o.w = __fdiv_rn(v.w, den);
        *(float4*)(fpn + e4) = o;
        ushort4 b; b.x = cvt_bf16(o.x); b.y = cvt_bf16(o.y);
        b.z = cvt_bf16(o.z); b.w = cvt_bf16(o.w);
        *(ushort4*)(fpb + e4) = b;
    }
}

// ---------------- Kernel 2 (fast): bf16 MFMA scoring + per-split top-16 -------
// Wave w: 16 queries (rows w*16+m) x 64 candidates (4 tiles of 16), K=512 in
// 16 MFMA steps. A frags preloaded in regs; B frags direct global (L1).
// C layout (m89): col=lane&15, row=(lane>>4)*4+reg.
__global__ __launch_bounds__(256, 4) void k_phase1_m(const unsigned short* __restrict__ fqb,
                                                     const unsigned short* __restrict__ fpb,
                                                     unsigned short* __restrict__ cand) {
    __shared__ __align__(16) float simb[QT * SIMP];

    const int b  = blockIdx.x & 7;
    const int i0 = ((blockIdx.x >> 3) & 31) * QT;
    const int js = blockIdx.x >> 8;
    const int tid = threadIdx.x;
    const int w = tid >> 6, lane = tid & 63;
    const int n16 = lane & 15, quad = lane >> 4;

    // preload A fragments for all K
    const unsigned short* Aq = fqb + ((size_t)b * NN + i0 + w * 16 + n16) * DD + quad * 8;
    bf16x8 afr[16];
#pragma unroll
    for (int kt = 0; kt < 16; ++kt)
        afr[kt] = *(const bf16x8*)(Aq + kt * 32);

    float tv[16]; int tix[16];
#pragma unroll
    for (int r = 0; r < 16; ++r) { tv[r] = -INFINITY; tix[r] = -1; }

    const int qq = tid >> 2;
    const int st = tid & 3;

    for (int jt = 0; jt < JRANGE / 64; ++jt) {   // 8 j-tiles of 64
        const int j0g = js * JRANGE + jt * 64;
        const unsigned short* Bq = fpb + ((size_t)b * NN + j0g) * DD + quad * 8;

        f32x4 acc[4];
#pragma unroll
        for (int ct = 0; ct < 4; ++ct) acc[ct] = (f32x4){0.f, 0.f, 0.f, 0.f};

#pragma unroll
        for (int kt = 0; kt < 16; ++kt) {
#pragma unroll
            for (int ct = 0; ct < 4; ++ct) {
                bf16x8 bfr = *(const bf16x8*)(Bq + ((size_t)(ct * 16 + n16)) * DD + kt * 32);
                acc[ct] = __builtin_amdgcn_mfma_f32_16x16x32_bf16(afr[kt], bfr, acc[ct], 0, 0, 0);
            }
        }

        __syncthreads();   // protect previous tile's selection reads
#pragma unroll
        for (int ct = 0; ct < 4; ++ct)
#pragma unroll
            for (int r = 0; r < 4; ++r)
                simb[(w * 16 + quad * 4 + r) * SIMP + ct * 16 + n16] = acc[ct][r];
        __syncthreads();

        // per-thread top-16 over this thread's 16-col stripe of its query
#pragma unroll
        for (int t = 0; t < 16; ++t) {
            const int jl = st * 16 + t;
            const float v = simb[qq * SIMP + jl];
            const int jg = j0g + jl;
            if (v > tv[0]) {
#pragma unroll
                for (int r = 0; r < 15; ++r) {
                    const bool up = tv[r + 1] < v;
                    const float nv = up ? tv[r + 1] : ((tv[r] < v) ? v : tv[r]);
                    const int   ni = up ? tix[r + 1] : ((tv[r] < v) ? jg : tix[r]);
                    tv[r] = nv; tix[r] = ni;
                }
                if (tv[15] < v) { tv[15] = v; tix[15] = jg; }
            }
        }
    }

    // merge 4 sorted 16-lists (lanes st=0..3 of query qq) -> split top-16
    __syncthreads();
    int p = 15;
    const size_t base = ((size_t)b * NN + i0 + qq) * MM + (size_t)js * 16;
    for (int m = 0; m < 16; ++m) {
        float cv = (p >= 0) ? tv[p] : -INFINITY;
        int   ci = (p >= 0) ? tix[p] : -1;
        float ov; int oi;
        ov = __shfl_xor(cv, 1, 4); oi = __shfl_xor(ci, 1, 4);
        if (ov > cv || (ov == cv && (unsigned)oi < (unsigned)ci)) { cv = ov; ci = oi; }
        ov = __shfl_xor(cv, 2, 4); oi = __shfl_xor(ci, 2, 4);
        if (ov > cv || (ov == cv && (unsigned)oi < (unsigned)ci)) { cv = ov; ci = oi; }
        if (p >= 0 && tv[p] == cv && tix[p] == ci) --p;
        if (st == 0) cand[base + m] = (unsigned short)ci;
    }
}

// ---------------- Kernel 2 (fallback): r9 fp32 GEMM phase-1 -------------------
#define JTILE 64
#define BK 16
#define LDP 68
__global__ __launch_bounds__(256, 4) void k_phase1_v(const float* __restrict__ ffq,
                                                     const float* __restrict__ ffp,
                                                     const float* __restrict__ rnp32,
                                                     unsigned short* __restrict__ cand) {
    __shared__ __align__(16) float As[BK * LDP];
    __shared__ __align__(16) float Bs[BK * LDP];
    __shared__ __align__(16) float simb[QT * SIMP];

    const int b  = blockIdx.x & 7;
    const int i0 = ((blockIdx.x >> 3) & 31) * QT;
    const int js = blockIdx.x >> 8;
    const int tid = threadIdx.x;
    const int tx = tid & 15, ty = tid >> 4;

    const float* Abase = ffq + ((size_t)b * NN + i0) * DD;
    const float* Bbase = ffp + (size_t)b * NN * DD;

    float tv[16]; int tix[16];
#pragma unroll
    for (int r = 0; r < 16; ++r) { tv[r] = -INFINITY; tix[r] = -1; }

    const int lrow = tid >> 2;
    const int lseg = (tid & 3) * 4;
    const int qq = tid >> 2;
    const int st = tid & 3;

    for (int jt = 0; jt < JRANGE / JTILE; ++jt) {
        const int j0 = js * JRANGE + jt * JTILE;
        float acc[4][4];
#pragma unroll
        for (int r = 0; r < 4; ++r)
#pragma unroll
            for (int c = 0; c < 4; ++c) acc[r][c] = 0.0f;

        for (int kt = 0; kt < DD / BK; ++kt) {
            const int k0 = kt * BK;
            __syncthreads();
            float4 av = *(const float4*)(Abase + (size_t)lrow * DD + k0 + lseg);
            float4 bv = *(const float4*)(Bbase + (size_t)(j0 + lrow) * DD + k0 + lseg);
            As[(lseg + 0) * LDP + lrow] = av.x; As[(lseg + 1) * LDP + lrow] = av.y;
            As[(lseg + 2) * LDP + lrow] = av.z; As[(lseg + 3) * LDP + lrow] = av.w;
            Bs[(lseg + 0) * LDP + lrow] = bv.x; Bs[(lseg + 1) * LDP + lrow] = bv.y;
            Bs[(lseg + 2) * LDP + lrow] = bv.z; Bs[(lseg + 3) * LDP + lrow] = bv.w;
            __syncthreads();
#pragma unroll
            for (int kk = 0; kk < BK; ++kk) {
                const float4 a4 = *(const float4*)&As[kk * LDP + ty * 4];
                const float4 b4 = *(const float4*)&Bs[kk * LDP + tx * 4];
                const float ar[4] = {a4.x, a4.y, a4.z, a4.w};
                const float br[4] = {b4.x, b4.y, b4.z, b4.w};
#pragma unroll
                for (int r = 0; r < 4; ++r)
#pragma unroll
                    for (int c = 0; c < 4; ++c)
                        acc[r][c] = fmaf(ar[r], br[c], acc[r][c]);
            }
        }
        float rp[4];
#pragma unroll
        for (int c = 0; c < 4; ++c) rp[c] = rnp32[b * NN + j0 + tx * 4 + c];
#pragma unroll
        for (int r = 0; r < 4; ++r) {
            float4 v4;
            v4.x = acc[r][0] * rp[0]; v4.y = acc[r][1] * rp[1];
            v4.z = acc[r][2] * rp[2]; v4.w = acc[r][3] * rp[3];
            *(float4*)&simb[(ty * 4 + r) * SIMP + tx * 4] = v4;
        }
        __syncthreads();

#pragma unroll
        for (int t = 0; t < 16; ++t) {
            const int jl = st * 16 + t;
            const float v = simb[qq * SIMP + jl];
            const int jg = j0 + jl;
            if (v > tv[0]) {
#pragma unroll
                for (int r = 0; r < 15; ++r) {
                    const bool up = tv[r + 1] < v;
                    const float nv = up ? tv[r + 1] : ((tv[r] < v) ? v : tv[r]);
                    const int   ni = up ? tix[r + 1] : ((tv[r] < v) ? jg : tix[r]);
                    tv[r] = nv; tix[r] = ni;
                }
                if (tv[15] < v) { tv[15] = v; tix[15] = jg; }
            }
        }
        __syncthreads();
    }

    int p = 15;
    const size_t base = ((size_t)b * NN + i0 + qq) * MM + (size_t)js * 16;
    for (int m = 0; m < 16; ++m) {
        float cv = (p >= 0) ? tv[p] : -INFINITY;
        int   ci = (p >= 0) ? tix[p] : -1;
        float ov; int oi;
        ov = __shfl_xor(cv, 1, 4); oi = __shfl_xor(ci, 1, 4);
        if (ov > cv || (ov == cv && (unsigned)oi < (unsigned)ci)) { cv = ov; ci = oi; }
        ov = __shfl_xor(cv, 2, 4); oi = __shfl_xor(ci, 2, 4);
        if (ov > cv || (ov == cv && (unsigned)oi < (unsigned)ci)) { cv = ov; ci = oi; }
        if (p >= 0 && tv[p] == cv && tix[p] == ci) --p;
        if (st == 0) cand[base + m] = (unsigned short)ci;
    }
}

// ---------------- 3x3 inverse (adjugate) apply ----------------
__device__ inline void inv3_apply(const double* a, double x0, double x1, double x2,
                                  double& y0, double& y1, double& y2) {
    double c00 = a[4]*a[8] - a[5]*a[7];
    double c01 = a[2]*a[7] - a[1]*a[8];
    double c02 = a[1]*a[5] - a[2]*a[4];
    double c10 = a[5]*a[6] - a[3]*a[8];
    double c11 = a[0]*a[8] - a[2]*a[6];
    double c12 = a[2]*a[3] - a[0]*a[5];
    double c20 = a[3]*a[7] - a[4]*a[6];
    double c21 = a[1]*a[6] - a[0]*a[7];
    double c22 = a[0]*a[4] - a[1]*a[3];
    double det = a[0]*c00 + a[1]*c10 + a[2]*c20;
    double id = 1.0 / det;
    y0 = (c00*x0 + c01*x1 + c02*x2) * id;
    y1 = (c10*x0 + c11*x1 + c12*x2) * id;
    y2 = (c20*x0 + c21*x1 + c22*x2) * id;
}

// =============== shared phase-2 body (templated on normalized source) =========
// VERIFIED r8 arithmetic: two ascending-k FMA chains split at d=384, one
// rounded add. Tie: value desc, index asc. DO NOT CHANGE ARITHMETIC.
template <bool PRE>   // PRE: normalized arrays precomputed (fast path)
__device__ inline void phase2_body(
        const float* __restrict__ qin, const float* __restrict__ ffq,
        const float* __restrict__ ffp, const float* __restrict__ R1,
        const float* __restrict__ R2, const int* __restrict__ cent,
        const float* __restrict__ W, const float* __restrict__ bvec,
        const float* __restrict__ normq, const float* __restrict__ normp,
        const float* __restrict__ fqn, const float* __restrict__ fpn,
        const unsigned short* __restrict__ cand, float* __restrict__ out) {
    const int b = blockIdx.x & 7;
    const int i = blockIdx.x >> 3;
    const int tid = threadIdx.x;
    const size_t qi = (size_t)b * NN + i;

    __shared__ float sfq[DD];
    __shared__ float sfqn[DD];
    __shared__ int cj[MM];
    __shared__ float pden_s[MM];
    __shared__ float sv[MM];
    __shared__ int sel[KK];
    __shared__ float meanf[DD], maxf[DD];
    __shared__ float red[3][4];

    if (PRE) {
        for (int d = tid; d < DD; d += 256) {
            sfq[d]  = ffq[qi * DD + d];
            sfqn[d] = fqn[qi * DD + d];
        }
    } else {
        const float qden = __fadd_rn(normq[qi], 1e-8f);
        for (int d = tid; d < DD; d += 256) {
            float xv = ffq[qi * DD + d];
            sfq[d] = xv;
            sfqn[d] = __fdiv_rn(xv, qden);
        }
    }
    if (tid < MM) {
        int j = (int)cand[qi * MM + tid];
        cj[tid] = j;
        if (!PRE) pden_s[tid] = __fadd_rn(normp[(size_t)b * NN + j], 1e-8f);
    }
    __syncthreads();

    if (tid < MM) {
        const int j = cj[tid];
        float acc1 = 0.0f, acc2 = 0.0f;
        if (PRE) {
            const float* fp = fpn + ((size_t)b * NN + j) * DD;
            for (int d = 0; d < KSPLIT; ++d) acc1 = fmaf(sfqn[d], fp[d], acc1);
            for (int d = KSPLIT; d < DD; ++d) acc2 = fmaf(sfqn[d], fp[d], acc2);
        } else {
            const float pd = pden_s[tid];
            const float* fp = ffp + ((size_t)b * NN + j) * DD;
            for (int d = 0; d < KSPLIT; ++d)
                acc1 = fmaf(sfqn[d], __fdiv_rn(fp[d], pd), acc1);
            for (int d = KSPLIT; d < DD; ++d)
                acc2 = fmaf(sfqn[d], __fdiv_rn(fp[d], pd), acc2);
        }
        sv[tid] = __fadd_rn(acc1, acc2);
    }
    __syncthreads();

    if (tid < MM) {
        const float v = sv[tid]; const int jj = cj[tid];
        int rank = 0;
        for (int t = 0; t < MM; ++t) {
            const float vt = sv[t]; const int jo = cj[t];
            rank += (vt > v) || (vt == v && jo < jj);
        }
        if (rank < KK) {
            sel[rank] = jj;
            out[(size_t)OUT3 + qi * KK + rank] = (float)jj;
        }
    }
    __syncthreads();

    for (int d = tid; d < DD; d += 256) {
        float sum = 0.0f, mx = -INFINITY;
#pragma unroll
        for (int k = 0; k < KK; ++k) {
            float v = ffp[((size_t)b * NN + sel[k]) * DD + d];
            sum += v; mx = fmaxf(mx, v);
        }
        meanf[d] = sum * (1.0f / 16.0f);
        maxf[d]  = mx;
    }
    __syncthreads();

    float a0 = 0.f, a1 = 0.f, a2 = 0.f;
    for (int d = tid; d < DD; d += 256) {
        const float x = sfq[d], m = meanf[d], mx = maxf[d];
        a0 = fmaf(W[d],        x, a0); a0 = fmaf(W[512 + d],        m, a0); a0 = fmaf(W[1024 + d],        mx, a0);
        a1 = fmaf(W[1536 + d], x, a1); a1 = fmaf(W[1536 + 512 + d], m, a1); a1 = fmaf(W[1536 + 1024 + d], mx, a1);
        a2 = fmaf(W[3072 + d], x, a2); a2 = fmaf(W[3072 + 512 + d], m, a2); a2 = fmaf(W[3072 + 1024 + d], mx, a2);
    }
#pragma unroll
    for (int off = 32; off > 0; off >>= 1) {
        a0 += __shfl_down(a0, off, 64);
        a1 += __shfl_down(a1, off, 64);
        a2 += __shfl_down(a2, off, 64);
    }
    const int lane = tid & 63, wid = tid >> 6;
    if (lane == 0) { red[0][wid] = a0; red[1][wid] = a1; red[2][wid] = a2; }
    __syncthreads();

    if (tid == 0) {
        double v0 = (double)bvec[0] + red[0][0] + red[0][1] + red[0][2] + red[0][3];
        double v1 = (double)bvec[1] + red[1][0] + red[1][1] + red[1][2] + red[1][3];
        double v2 = (double)bvec[2] + red[2][0] + red[2][1] + red[2][2] + red[2][3];
        double r1[9], r2[9];
#pragma unroll
        for (int t = 0; t < 9; ++t) { r1[t] = R1[qi * 9 + t]; r2[t] = R2[qi * 9 + t]; }
        double u0, u1, u2, w0, w1, w2;
        inv3_apply(r1, v0, v1, v2, u0, u1, u2);
        inv3_apply(r2, u0, u1, u2, w0, w1, w2);
        const float mask = (cent[qi] >= NN) ? 1.0f : 0.0f;
        const float q0 = qin[qi * 3 + 0], q1 = qin[qi * 3 + 1], q2 = qin[qi * 3 + 2];
        out[qi * 3 + 0] = q0; out[qi * 3 + 1] = q1; out[qi * 3 + 2] = q2;
        const float o0 = q0 + (float)w0 * mask;
        const float o1 = q1 + (float)w1 * mask;
        const float o2 = q2 + (float)w2 * mask;
        out[OUT1 + qi * 3 + 0] = o0; out[OUT1 + qi * 3 + 1] = o1; out[OUT1 + qi * 3 + 2] = o2;
        out[OUT2 + qi * 3 + 0] = o0; out[OUT2 + qi * 3 + 1] = o1; out[OUT2 + qi * 3 + 2] = o2;
    }
}

__global__ __launch_bounds__(256) void k_phase2_f(
        const float* qin, const float* ffq, const float* ffp, const float* R1,
        const float* R2, const int* cent, const float* W, const float* bvec,
        const float* fqn, const float* fpn, const unsigned short* cand, float* out) {
    phase2_body<true>(qin, ffq, ffp, R1, R2, cent, W, bvec,
                      nullptr, nullptr, fqn, fpn, cand, out);
}

__global__ __launch_bounds__(256) void k_phase2_v(
        const float* qin, const float* ffq, const float* ffp, const float* R1,
        const float* R2, const int* cent, const float* W, const float* bvec,
        const float* normq, const float* normp, const unsigned short* cand, float* out) {
    phase2_body<false>(qin, ffq, ffp, R1, R2, cent, W, bvec,
                       normq, normp, nullptr, nullptr, cand, out);
}

extern "C" void kernel_launch(void* const* d_in, const int* in_sizes, int n_in,
                              void* d_out, int out_size, void* d_ws, size_t ws_size,
                              hipStream_t stream) {
    (void)in_sizes; (void)n_in; (void)out_size;
    const float* q   = (const float*)d_in[1];
    const float* ffp = (const float*)d_in[2];
    const float* ffq = (const float*)d_in[3];
    const float* R1  = (const float*)d_in[4];
    const float* R2  = (const float*)d_in[5];
    const int*   ct  = (const int*)d_in[6];
    const float* W   = (const float*)d_in[7];
    const float* bb  = (const float*)d_in[8];
    float* out = (float*)d_out;

    float* normq = (float*)d_ws;                               // BN
    float* normp = normq + BN;                                 // BN
    float* rnp32 = normp + BN;                                 // BN
    unsigned short* cand = (unsigned short*)(rnp32 + BN);      // BN*MM u16
    float* fqn = (float*)(cand + (size_t)BN * MM);             // BN*DD
    float* fpn = fqn + (size_t)BN * DD;                        // BN*DD
    unsigned short* fqb = (unsigned short*)(fpn + (size_t)BN * DD);  // BN*DD u16
    unsigned short* fpb = fqb + (size_t)BN * DD;               // BN*DD u16

    const size_t need = (size_t)BN * (35 * 4 + 2 * DD * 4 + 2 * DD * 2);

    k_norm_np<<<dim3((2 * BN) / 32), dim3(256), 0, stream>>>(ffq, ffp, normq, normp, rnp32);

    if (ws_size >= need) {
        k_normalize<<<dim3((BN * DD) / 1024), dim3(256), 0, stream>>>(
            ffq, ffp, normq, normp, fqn, fpn, fqb, fpb);
        k_phase1_m<<<dim3(BB * (NN / QT) * JSPLIT), dim3(256), 0, stream>>>(fqb, fpb, cand);
        k_phase2_f<<<dim3(BB * NN), dim3(256), 0, stream>>>(q, ffq, ffp, R1, R2, ct, W, bb,
                                                            fqn, fpn, cand, out);
    } else {
        k_phase1_v<<<dim3(BB * (NN / QT) * JSPLIT), dim3(256), 0, stream>>>(ffq, ffp, rnp32, cand);
        k_phase2_v<<<dim3(BB * NN), dim3(256), 0, stream>>>(q, ffq, ffp, R1, R2, ct, W, bb,
                                                            normq, normp, cand, out);
    }
}